// Round 16
// baseline (21.471 us; speedup 1.0000x reference)
//
#include <hip/hip_runtime.h>
#include <math.h>

#define NSAMP 32
#define HW 512
#define PW 128
#define NPOOL (PW * PW)                 // 16384 pooled elements / sample
#define BPS 16                          // blocks per sample
#define NBLOCKS (NSAMP * BPS)           // 512 (2 blocks / CU, all co-resident)
#define PPT 4                           // pooled patches per thread
#define NACC 14

typedef float f32x4 __attribute__((ext_vector_type(4)));
typedef unsigned long long u64;

// ws layout (all logic init-free; counters never reset, snapshot-at-entry):
//   byte 64*s   : u64 counter for sample s (one per 64B line), s<32
//   byte 2048   : u64 final counter
//   byte 4096   : float part[NACC][NBLOCKS]  (28 KB, overwritten each call)
//   byte 36864  : double res[NSAMP][3]       (768 B, overwritten each call)

__device__ __forceinline__ float agloadf(const float* p) {
    return __hip_atomic_load(p, __ATOMIC_RELAXED, __HIP_MEMORY_SCOPE_AGENT);
}
__device__ __forceinline__ void agstoref(float* p, float v) {
    __hip_atomic_store(p, v, __ATOMIC_RELAXED, __HIP_MEMORY_SCOPE_AGENT);
}
__device__ __forceinline__ double agloadd(const double* p) {
    u64 u = __hip_atomic_load((const u64*)p, __ATOMIC_RELAXED, __HIP_MEMORY_SCOPE_AGENT);
    return __longlong_as_double((long long)u);
}
__device__ __forceinline__ void agstored(double* p, double v) {
    __hip_atomic_store((u64*)p, (u64)__double_as_longlong(v),
                       __ATOMIC_RELAXED, __HIP_MEMORY_SCOPE_AGENT);
}
__device__ __forceinline__ u64 agloadu(const u64* p) {
    return __hip_atomic_load(p, __ATOMIC_RELAXED, __HIP_MEMORY_SCOPE_AGENT);
}
__device__ __forceinline__ u64 agbump(u64* p) {
    return __hip_atomic_fetch_add(p, 1ULL, __ATOMIC_RELAXED, __HIP_MEMORY_SCOPE_AGENT);
}

// two 16B loads from one base (rows r, r+1 of a 512-float row pitch)
__device__ __forceinline__ void gload2x4(f32x4& r0, f32x4& r1, const float* p) {
    asm volatile("global_load_dwordx4 %0, %2, off\n\t"
                 "global_load_dwordx4 %1, %2, off offset:2048"
                 : "=v"(r0), "=v"(r1) : "v"(p) : "memory");
}
// four scalar loads at +0,+1024,+2048,+3072 bytes
__device__ __forceinline__ void gload4(float& a, float& b, float& c, float& d,
                                       const float* p) {
    asm volatile("global_load_dword %0, %4, off\n\t"
                 "global_load_dword %1, %4, off offset:1024\n\t"
                 "global_load_dword %2, %4, off offset:2048\n\t"
                 "global_load_dword %3, %4, off offset:3072"
                 : "=v"(a), "=v"(b), "=v"(c), "=v"(d) : "v"(p) : "memory");
}

#define WAITV(n)  do { asm volatile("s_waitcnt vmcnt(" #n ")" ::: "memory"); \
                       __builtin_amdgcn_sched_barrier(0); } while (0)

// full-wave (64 lane) sum via DPP on the VALU pipe; result valid in lane 63
__device__ __forceinline__ float wave_sum_dpp(float x) {
#define DPP_ADD(ctrl)                                                         \
    x += __int_as_float(__builtin_amdgcn_update_dpp(                          \
        0, __float_as_int(x), (ctrl), 0xf, 0xf, true));
    DPP_ADD(0x111)
    DPP_ADD(0x112)
    DPP_ADD(0x114)
    DPP_ADD(0x118)
    DPP_ADD(0x142)
    DPP_ADD(0x143)
#undef DPP_ADD
    return x;
}

__global__ __launch_bounds__(256) void covloss_fused(
    const float* __restrict__ logits, const float* __restrict__ labels,
    const float* __restrict__ v_att,  const float* __restrict__ h_att,
    float* __restrict__ out, u64* __restrict__ ws)
{
    const int bid   = blockIdx.x;
    const int n     = bid >> 4;              // sample
    const int local = bid & 15;              // block within sample
    const int pbase = local * (PPT * 256);
    const int tid   = threadIdx.x;

    u64*    cnt_s = (u64*)((char*)ws + 64 * n);
    u64*    cnt_f = (u64*)((char*)ws + 2048);
    float*  part  = (float*)((char*)ws + 4096);
    double* res   = (double*)((char*)ws + 36864);

    // snapshot counters BEFORE any block can increment (all 512 co-resident;
    // first increment happens >=10us after dispatch ramp)
    u64 s0 = 0, f0 = 0;
    if (tid == 0) { s0 = agloadu(cnt_s); f0 = agloadu(cnt_f); }

    const float* lg = logits + (size_t)n * HW * HW;
    const float* lb = labels + (size_t)n * HW * HW;

    float bce = 0.f, inter = 0.f, ysum = 0.f;
    unsigned long long cnt_u = 0;            // wave-uniform via ballot (SALU)
    float S_v = 0.f, S_h = 0.f, S_l = 0.f;
    float S_vv = 0.f, S_hh = 0.f, S_ll = 0.f;
    float S_vh = 0.f, S_vl = 0.f, S_hl = 0.f, S_vhl = 0.f;

    // two named register buffer sets (A, B): 8 f32x4 each
    f32x4 LA0, LA1, LA2, LA3, YA0, YA1, YA2, YA3;
    f32x4 LB0, LB1, LB2, LB3, YB0, YB1, YB2, YB3;
    float v0, v1, v2, v3, h0, h1, h2, h3;

#define STAGE(S, p) do {                                                      \
    const int pidx = pbase + (p) * 256 + tid;                                 \
    const int pr = pidx >> 7, pc = pidx & 127;                                \
    const float* baL = lg + (size_t)(4 * pr) * HW + 4 * pc;                   \
    const float* baY = lb + (size_t)(4 * pr) * HW + 4 * pc;                   \
    gload2x4(L##S##0, L##S##1, baL);                                          \
    gload2x4(L##S##2, L##S##3, baL + 2 * HW);                                 \
    gload2x4(Y##S##0, Y##S##1, baY);                                          \
    gload2x4(Y##S##2, Y##S##3, baY + 2 * HW);                                 \
} while (0)

#define ROW(Lr, Yr) do {                                                      \
    _Pragma("unroll")                                                         \
    for (int j = 0; j < 4; ++j) {                                             \
        const float pp = (Lr)[j], y = (Yr)[j];                                \
        bce = fmaf(y, __log2f(pp), bce);                                      \
        bce = fmaf(1.f - y, __log2f(1.f - pp), bce);                          \
        const bool m = pp > 0.4f;                                             \
        cnt_u += __popcll(__ballot(m));                                       \
        inter += m ? y : 0.f;                                                 \
        lsum  += y;                                                           \
    }                                                                         \
} while (0)

#define COMPUTE(S, vS, hS) do {                                               \
    float lsum = 0.f;                                                         \
    ROW(L##S##0, Y##S##0); ROW(L##S##1, Y##S##1);                             \
    ROW(L##S##2, Y##S##2); ROW(L##S##3, Y##S##3);                             \
    ysum += lsum;                                                             \
    const float l = lsum * 0.0625f;                                           \
    S_v += vS; S_h += hS; S_l += l;                                           \
    S_vv = fmaf(vS, vS, S_vv); S_hh = fmaf(hS, hS, S_hh);                     \
    S_ll = fmaf(l, l, S_ll);                                                  \
    const float vh = vS * hS;                                                 \
    S_vh += vh; S_vl = fmaf(vS, l, S_vl); S_hl = fmaf(hS, l, S_hl);           \
    S_vhl = fmaf(vh, l, S_vhl);                                               \
} while (0)

    // --- prologue: 8 scalar vh loads + patches 0,1 in flight ---
    gload4(v0, v1, v2, v3, v_att + (size_t)n * NPOOL + pbase + tid);
    gload4(h0, h1, h2, h3, h_att + (size_t)n * NPOOL + pbase + tid);
    STAGE(A, 0);
    STAGE(B, 1);

    WAITV(8);            // (entry snaps+)vh+patch0 retired; patch1 in flight
    COMPUTE(A, v0, h0);
    STAGE(A, 2);
    WAITV(8);            // patch1 retired; patch2 in flight
    COMPUTE(B, v1, h1);
    STAGE(B, 3);
    WAITV(8);            // patch2 retired; patch3 in flight
    COMPUTE(A, v2, h2);
    WAITV(0);            // patch3 retired
    COMPUTE(B, v3, h3);

#undef STAGE
#undef ROW
#undef COMPUTE

    float vals[13] = { bce, inter, ysum,
                       S_v, S_h, S_l, S_vv, S_hh, S_ll,
                       S_vh, S_vl, S_hl, S_vhl };
#pragma unroll
    for (int k = 0; k < 13; ++k) vals[k] = wave_sum_dpp(vals[k]);

    __shared__ float sh[4][NACC];
    const int lane = tid & 63, wv = tid >> 6;
    if (lane == 63) {
        sh[wv][0] = vals[0];
        sh[wv][1] = (float)cnt_u;
        sh[wv][2] = vals[1];
        sh[wv][3] = vals[2];
#pragma unroll
        for (int k = 3; k < 13; ++k) sh[wv][k + 1] = vals[k];
    }
    __syncthreads();

    // publish block partials (write-through to coherent point; no init needed)
    if (tid < NACC) {
        const float p = sh[0][tid] + sh[1][tid] + sh[2][tid] + sh[3][tid];
        agstoref(&part[(size_t)tid * NBLOCKS + bid], p);
    }

    // ---- level 1: per-sample rendezvous (16 incs on a private 64B line) ----
    __shared__ int sampWin;
    if (tid == 0) {
        WAITV(0);                            // drain wave-0 part stores
        const u64 old = agbump(cnt_s);
        sampWin = (old == s0 + (BPS - 1));
    }
    __syncthreads();
    if (!sampWin) return;

    // sample winner: threads 0..13 each sum their moment over 16 blocks
    __shared__ double accd[NACC];
    if (tid < NACC) {
        const float* p = part + (size_t)tid * NBLOCKS + n * BPS;
        double a = 0.0;
#pragma unroll
        for (int i = 0; i < BPS; ++i) a += (double)agloadf(p + i);
        accd[tid] = a;
    }
    __syncthreads();

    // ---- level 2: final rendezvous across the 32 sample winners ----
    __shared__ int finWin;
    if (tid == 0) {
        const double* a = accd;
        const double nn = (double)NPOOL;
        const double cvv = a[7] - a[4] * a[4] / nn;
        const double chh = a[8] - a[5] * a[5] / nn;
        const double cll = a[9] - a[6] * a[6] / nn;
        const double num = a[13]
            - (a[4] * a[12] + a[5] * a[11] + a[6] * a[10]) / nn
            + 2.0 * a[4] * a[5] * a[6] / (nn * nn);
        agstored(&res[n * 3 + 0], a[0]);                               // bce_s
        agstored(&res[n * 3 + 1], 2.0 * (a[2] + 1.0) / (a[1] + a[3] + 1.0));
        agstored(&res[n * 3 + 2], num / sqrt(cvv * chh * cll));        // cor_s
        WAITV(0);                            // drain res stores
        const u64 old2 = agbump(cnt_f);
        finWin = (old2 == f0 + (NSAMP - 1));
    }
    __syncthreads();
    if (!finWin) return;

    // final winner: sum 32 samples in fixed order, write the scalar
    __shared__ double rb[NSAMP], rd[NSAMP], rc[NSAMP];
    if (tid < NSAMP) {
        rb[tid] = agloadd(&res[tid * 3 + 0]);
        rd[tid] = agloadd(&res[tid * 3 + 1]);
        rc[tid] = agloadd(&res[tid * 3 + 2]);
    }
    __syncthreads();
    if (tid == 0) {
        double bces = 0.0, ds = 0.0, cs = 0.0;
#pragma unroll
        for (int i = 0; i < NSAMP; ++i) { bces += rb[i]; ds += rd[i]; cs += rc[i]; }
        const double bceloss = -(bces * M_LN2) / ((double)NSAMP * HW * HW);
        out[0] = (float)(0.2 * bceloss + 0.3 * (1.0 - ds / NSAMP) + 0.5 * (-cs / NSAMP));
    }
}

extern "C" void kernel_launch(void* const* d_in, const int* in_sizes, int n_in,
                              void* d_out, int out_size, void* d_ws, size_t ws_size,
                              hipStream_t stream) {
    const float* logits = (const float*)d_in[0];
    const float* labels = (const float*)d_in[1];
    const float* v_att  = (const float*)d_in[2];
    const float* h_att  = (const float*)d_in[3];
    float* out = (float*)d_out;
    u64*   ws  = (u64*)d_ws;

    covloss_fused<<<NBLOCKS, 256, 0, stream>>>(logits, labels, v_att, h_att, out, ws);
}

// Round 17
// 20.698 us; speedup vs baseline: 1.0374x; 1.0374x over previous
//
#include <hip/hip_runtime.h>
#include <math.h>

#define NSAMP 32
#define HW 512
#define PW 128
#define NPOOL (PW * PW)                 // 16384 pooled elements / sample
#define BPS 8                           // blocks per sample
#define NBLOCKS (NSAMP * BPS)           // 256 blocks (1 per CU), 512 threads each
#define NTHR 512
#define PPT 4                           // pooled patches per thread
#define NACC 14

typedef float f32x4 __attribute__((ext_vector_type(4)));

// two 16B loads from one base (rows r, r+1 of a 512-float row pitch)
__device__ __forceinline__ void gload2x4(f32x4& r0, f32x4& r1, const float* p) {
    asm volatile("global_load_dwordx4 %0, %2, off\n\t"
                 "global_load_dwordx4 %1, %2, off offset:2048"
                 : "=v"(r0), "=v"(r1) : "v"(p) : "memory");
}
// two scalar loads at +0,+2048 bytes (512-float patch spacing)
__device__ __forceinline__ void gload2(float& a, float& b, const float* p) {
    asm volatile("global_load_dword %0, %2, off\n\t"
                 "global_load_dword %1, %2, off offset:2048"
                 : "=v"(a), "=v"(b) : "v"(p) : "memory");
}

#define WAITV(n)  do { asm volatile("s_waitcnt vmcnt(" #n ")" ::: "memory"); \
                       __builtin_amdgcn_sched_barrier(0); } while (0)

// full-wave (64 lane) sum via DPP on the VALU pipe; result valid in lane 63
__device__ __forceinline__ float wave_sum_dpp(float x) {
#define DPP_ADD(ctrl)                                                         \
    x += __int_as_float(__builtin_amdgcn_update_dpp(                          \
        0, __float_as_int(x), (ctrl), 0xf, 0xf, true));
    DPP_ADD(0x111)
    DPP_ADD(0x112)
    DPP_ADD(0x114)
    DPP_ADD(0x118)
    DPP_ADD(0x142)
    DPP_ADD(0x143)
#undef DPP_ADD
    return x;
}

__global__ __launch_bounds__(NTHR) void covloss_main(
    const float* __restrict__ logits, const float* __restrict__ labels,
    const float* __restrict__ v_att,  const float* __restrict__ h_att,
    float* __restrict__ part)
{
    const int bid   = blockIdx.x;
    const int n     = bid >> 3;              // sample
    const int local = bid & 7;               // block within sample
    const int pbase = local * (PPT * NTHR);  // 2048 pooled elems per block
    const int tid   = threadIdx.x;

    const float* lg = logits + (size_t)n * HW * HW;
    const float* lb = labels + (size_t)n * HW * HW;

    float bce = 0.f, inter = 0.f, ysum = 0.f;
    unsigned long long cnt_u = 0;            // wave-uniform via ballot (SALU)
    float S_v = 0.f, S_h = 0.f, S_l = 0.f;
    float S_vv = 0.f, S_hh = 0.f, S_ll = 0.f;
    float S_vh = 0.f, S_vl = 0.f, S_hl = 0.f, S_vhl = 0.f;

    // two named register buffer sets (A, B): 8 f32x4 each
    f32x4 LA0, LA1, LA2, LA3, YA0, YA1, YA2, YA3;
    f32x4 LB0, LB1, LB2, LB3, YB0, YB1, YB2, YB3;
    float v0, v1, v2, v3, h0, h1, h2, h3;

#define STAGE(S, p) do {                                                      \
    const int pidx = pbase + (p) * NTHR + tid;                                \
    const int pr = pidx >> 7, pc = pidx & 127;                                \
    const float* baL = lg + (size_t)(4 * pr) * HW + 4 * pc;                   \
    const float* baY = lb + (size_t)(4 * pr) * HW + 4 * pc;                   \
    gload2x4(L##S##0, L##S##1, baL);                                          \
    gload2x4(L##S##2, L##S##3, baL + 2 * HW);                                 \
    gload2x4(Y##S##0, Y##S##1, baY);                                          \
    gload2x4(Y##S##2, Y##S##3, baY + 2 * HW);                                 \
} while (0)

#define ROW(Lr, Yr) do {                                                      \
    _Pragma("unroll")                                                         \
    for (int j = 0; j < 4; ++j) {                                             \
        const float pp = (Lr)[j], y = (Yr)[j];                                \
        bce = fmaf(y, __log2f(pp), bce);                                      \
        bce = fmaf(1.f - y, __log2f(1.f - pp), bce);                          \
        const bool m = pp > 0.4f;                                             \
        cnt_u += __popcll(__ballot(m));                                       \
        inter += m ? y : 0.f;                                                 \
        lsum  += y;                                                           \
    }                                                                         \
} while (0)

#define COMPUTE(S, vS, hS) do {                                               \
    float lsum = 0.f;                                                         \
    ROW(L##S##0, Y##S##0); ROW(L##S##1, Y##S##1);                             \
    ROW(L##S##2, Y##S##2); ROW(L##S##3, Y##S##3);                             \
    ysum += lsum;                                                             \
    const float l = lsum * 0.0625f;                                           \
    S_v += vS; S_h += hS; S_l += l;                                           \
    S_vv = fmaf(vS, vS, S_vv); S_hh = fmaf(hS, hS, S_hh);                     \
    S_ll = fmaf(l, l, S_ll);                                                  \
    const float vh = vS * hS;                                                 \
    S_vh += vh; S_vl = fmaf(vS, l, S_vl); S_hl = fmaf(hS, l, S_hl);           \
    S_vhl = fmaf(vh, l, S_vhl);                                               \
} while (0)

    // --- prologue: 8 scalar vh loads (patch spacing 512 floats = 2048 B,
    //     split into two pairs to stay within the 13-bit offset) ---
    const float* vb = v_att + (size_t)n * NPOOL + pbase + tid;
    const float* hb = h_att + (size_t)n * NPOOL + pbase + tid;
    gload2(v0, v1, vb);
    gload2(v2, v3, vb + 2 * NTHR);
    gload2(h0, h1, hb);
    gload2(h2, h3, hb + 2 * NTHR);
    STAGE(A, 0);
    STAGE(B, 1);

    WAITV(8);            // vh + patch0 retired; patch1 in flight
    COMPUTE(A, v0, h0);
    STAGE(A, 2);         // reuse A regs (dead) for patch2
    WAITV(8);            // patch1 retired; patch2 in flight
    COMPUTE(B, v1, h1);
    STAGE(B, 3);
    WAITV(8);            // patch2 retired; patch3 in flight
    COMPUTE(A, v2, h2);
    WAITV(0);            // patch3 retired
    COMPUTE(B, v3, h3);

#undef STAGE
#undef ROW
#undef COMPUTE

    // 13 lane-varying accumulators; cnt_u is wave-uniform
    float vals[13] = { bce, inter, ysum,
                       S_v, S_h, S_l, S_vv, S_hh, S_ll,
                       S_vh, S_vl, S_hl, S_vhl };
#pragma unroll
    for (int k = 0; k < 13; ++k) vals[k] = wave_sum_dpp(vals[k]);

    __shared__ float sh[8][NACC];
    const int lane = tid & 63, wv = tid >> 6;
    if (lane == 63) {
        sh[wv][0] = vals[0];
        sh[wv][1] = (float)cnt_u;
        sh[wv][2] = vals[1];
        sh[wv][3] = vals[2];
#pragma unroll
        for (int k = 3; k < 13; ++k) sh[wv][k + 1] = vals[k];
    }
    __syncthreads();
    if (tid < NACC) {
        float s = sh[0][tid];
#pragma unroll
        for (int w = 1; w < 8; ++w) s += sh[w][tid];
        part[(size_t)tid * NBLOCKS + bid] = s;
    }
}

__global__ __launch_bounds__(256) void covloss_finalize(
    const float* __restrict__ part, float* __restrict__ out)
{
    const int t = threadIdx.x;
    __shared__ double acc[NSAMP][NACC];

    // 448 (sample, moment) pairs; each = sum of BPS=8 contiguous floats
    for (int pair = t; pair < NSAMP * NACC; pair += 256) {
        const int s = pair / NACC, k = pair % NACC;
        const float4* p = (const float4*)(part + (size_t)k * NBLOCKS + s * BPS);
        double a = 0.0;
#pragma unroll
        for (int i = 0; i < 2; ++i) {
            const float4 q = p[i];
            a += (double)q.x + (double)q.y + (double)q.z + (double)q.w;
        }
        acc[s][k] = a;
    }
    __syncthreads();

    __shared__ double sb[NSAMP], sd[NSAMP], sc[NSAMP];
    if (t < NSAMP) {
        const double* a = acc[t];
        const double nn = (double)NPOOL;
        const double cvv = a[7] - a[4] * a[4] / nn;
        const double chh = a[8] - a[5] * a[5] / nn;
        const double cll = a[9] - a[6] * a[6] / nn;
        const double num = a[13]
            - (a[4] * a[12] + a[5] * a[11] + a[6] * a[10]) / nn
            + 2.0 * a[4] * a[5] * a[6] / (nn * nn);
        sc[t] = num / sqrt(cvv * chh * cll);
        sd[t] = 2.0 * (a[2] + 1.0) / (a[1] + a[3] + 1.0);
        sb[t] = a[0];
    }
    __syncthreads();
    if (t == 0) {
        double bces = 0.0, ds = 0.0, cs = 0.0;
#pragma unroll
        for (int i = 0; i < NSAMP; ++i) { bces += sb[i]; ds += sd[i]; cs += sc[i]; }
        const double bceloss = -(bces * M_LN2) / ((double)NSAMP * HW * HW);
        out[0] = (float)(0.2 * bceloss + 0.3 * (1.0 - ds / NSAMP) + 0.5 * (-cs / NSAMP));
    }
}

extern "C" void kernel_launch(void* const* d_in, const int* in_sizes, int n_in,
                              void* d_out, int out_size, void* d_ws, size_t ws_size,
                              hipStream_t stream) {
    const float* logits = (const float*)d_in[0];
    const float* labels = (const float*)d_in[1];
    const float* v_att  = (const float*)d_in[2];
    const float* h_att  = (const float*)d_in[3];
    float* out  = (float*)d_out;
    float* part = (float*)d_ws;   // NACC * NBLOCKS floats = 14 KB

    covloss_main<<<NBLOCKS, NTHR, 0, stream>>>(logits, labels, v_att, h_att, part);
    covloss_finalize<<<1, 256, 0, stream>>>(part, out);
}